// Round 7
// baseline (443.324 us; speedup 1.0000x reference)
//
#include <hip/hip_runtime.h>

typedef __bf16 bf16x8 __attribute__((ext_vector_type(8)));
typedef float f32x4 __attribute__((ext_vector_type(4)));
typedef unsigned short u16x4 __attribute__((ext_vector_type(4)));
typedef unsigned short u16x8 __attribute__((ext_vector_type(8)));

#define KP 2112   // padded K: 2080 + 32 = 33 * 64
#define NKT 66    // K-tiles of 32

__device__ __forceinline__ unsigned short f2bf(float f) {
  unsigned int u = __builtin_bit_cast(unsigned int, f);
  u += 0x7FFFu + ((u >> 16) & 1u);   // round-to-nearest-even
  return (unsigned short)(u >> 16);
}

__device__ __forceinline__ bf16x8 ld_frag(const unsigned short* p) {
  return __builtin_bit_cast(bf16x8, *(const u16x8*)p);
}

#define MFMA16(a, b, c) __builtin_amdgcn_mfma_f32_16x16x32_bf16((a), (b), (c), 0, 0, 0)

// async global->LDS, 16B per lane (global_load_lds_dwordx4)
__device__ __forceinline__ void cp16(const void* g, void* l) {
  __builtin_amdgcn_global_load_lds(
      (const __attribute__((address_space(1))) unsigned int*)g,
      (__attribute__((address_space(3))) unsigned int*)l, 16, 0, 0);
}

__device__ __forceinline__ void close_bar() {
  asm volatile("" ::: "memory");
  __builtin_amdgcn_s_barrier();
  __builtin_amdgcn_sched_barrier(0);
}

#define VMWAIT(N) asm volatile("s_waitcnt vmcnt(" #N ")" ::: "memory")

// ---------------------------------------------------------------------------
// Coalesced triangular emit: 2112 u16 per matrix as u16x8 per thread (+ tail
// jobs on tid<8). (i,j) recovered analytically from flat idx p via sqrt+fixup.
// ---------------------------------------------------------------------------
__device__ __forceinline__ void emit_tri(const unsigned short* __restrict__ sK,
                                         unsigned short* __restrict__ dst,
                                         bool upper, int tid) {
#pragma unroll
  for (int jj = 0; jj < 2; ++jj) {
    if (jj == 1 && tid >= 8) break;
    const int p0 = (jj == 0) ? tid * 8 : 2048 + tid * 8;
    int i, j;
    if (upper) {
      // U_i = i*(129-i)/2 rows start; row i spans [U_i, U_{i+1}) len 64-i
      float s = sqrtf(4160.25f - 2.0f * (float)p0);
      i = (int)(64.5f - s);
      if (i < 0) i = 0;
      if (i > 63) i = 63;
      while (i > 0 && i * (129 - i) / 2 > p0) --i;
      while (i < 63 && (i + 1) * (128 - i) / 2 <= p0) ++i;
      j = i + (p0 - i * (129 - i) / 2);
    } else {
      // T_i = i*(i+1)/2; row i spans [T_i, T_{i+1}) len i+1
      float s = sqrtf(8.0f * (float)p0 + 1.0f);
      i = (int)((s - 1.0f) * 0.5f);
      if (i < 0) i = 0;
      if (i > 63) i = 63;
      while (i > 0 && i * (i + 1) / 2 > p0) --i;
      while (i < 63 && (i + 1) * (i + 2) / 2 <= p0) ++i;
      j = p0 - i * (i + 1) / 2;
    }
    u16x8 o;
#pragma unroll
    for (int e = 0; e < 8; ++e) {
      const int p = p0 + e;
      o[e] = (p < 2080 && i < 64) ? sK[i * 64 + j] : (unsigned short)0;
      if (upper) { if (++j > 63) { ++i; j = i; } }
      else       { if (++j > i)  { ++i; j = 0; } }
    }
    *(u16x8*)(dst + p0) = o;
  }
}

// ---------------------------------------------------------------------------
// Fused prep: blocks [0,4096) = per-batch kp (E*W*E^T -> triu/tril + E copy);
// blocks [4096,6144) = W_triu/W_tril fp32->bf16 with K-pad (2 rows each).
// ---------------------------------------------------------------------------
__global__ __launch_bounds__(256) void prep_all(
    const float* __restrict__ E,        // [B,64,64]
    const float* __restrict__ Wkp,      // [64,64]
    const float* __restrict__ Wtriu,    // [4096,2080]
    const float* __restrict__ Wtril,    // [4096,2080]
    float* __restrict__ out0,           // [B,4096]
    unsigned short* __restrict__ triu,  // [B,2112] bf16
    unsigned short* __restrict__ tril,  // [B,2112] bf16
    unsigned short* __restrict__ Wu,    // [4096,2112] bf16
    unsigned short* __restrict__ Wl)    // [4096,2112] bf16
{
  const int bid = blockIdx.x;
  const int tid = threadIdx.x;

  if (bid >= 4096) {
    // ---- cvt path: 2 rows of each W matrix, coalesced float4 -> u16x4
    const int r0 = (bid - 4096) * 2;
#pragma unroll
    for (int q = 0; q < 4; ++q) {
      const int row = r0 + (q & 1);
      const float* src = (q < 2 ? Wtriu : Wtril) + (size_t)row * 2080;
      unsigned short* dst = (q < 2 ? Wu : Wl) + (size_t)row * KP;
      for (int c = tid; c < 528; c += 256) {   // u16x4 chunks per row
        u16x4 o = {0, 0, 0, 0};
        if (c < 520) {
          float4 v = *(const float4*)(src + c * 4);
          o[0] = f2bf(v.x); o[1] = f2bf(v.y); o[2] = f2bf(v.z); o[3] = f2bf(v.w);
        }
        ((u16x4*)dst)[c] = o;
      }
    }
    return;
  }

  // ---- batch path
  __shared__ __align__(16) unsigned short sE[64 * 64];
  __shared__ __align__(16) unsigned short sWt[64 * 64];  // reused as sK later
  __shared__ __align__(16) unsigned short sT[64 * 64];

  const int b = bid;
  const float* Eb = E + (size_t)b * 4096;
  float* o0 = out0 + (size_t)b * 4096;

#pragma unroll
  for (int it = 0; it < 4; ++it) {
    const int flat = it * 1024 + tid * 4;
    float4 v = *(const float4*)(Eb + flat);
    *(float4*)(o0 + flat) = v;                 // embs_flatten output (exact fp32)
    u16x4 e;
    e[0] = f2bf(v.x); e[1] = f2bf(v.y); e[2] = f2bf(v.z); e[3] = f2bf(v.w);
    *(u16x4*)(sE + flat) = e;
    float4 wv = *(const float4*)(Wkp + flat);  // inline W^T (row d, cols c0..+3)
    const int d = flat >> 6, c0 = flat & 63;
    sWt[(c0 + 0) * 64 + d] = f2bf(wv.x);
    sWt[(c0 + 1) * 64 + d] = f2bf(wv.y);
    sWt[(c0 + 2) * 64 + d] = f2bf(wv.z);
    sWt[(c0 + 3) * 64 + d] = f2bf(wv.w);
  }
  __syncthreads();

  const int lane = tid & 63, w = tid >> 6;
  const int fr = lane & 15;
  const int fk = (lane >> 4) << 3;
  const int qr = (lane >> 4) << 2;

  // T = Ebf * Wkp : wave w computes rows [w*16, w*16+16)
#pragma unroll
  for (int ct = 0; ct < 4; ++ct) {
    f32x4 acc = {0.f, 0.f, 0.f, 0.f};
#pragma unroll
    for (int k2 = 0; k2 < 2; ++k2) {
      bf16x8 a = ld_frag(sE + (w * 16 + fr) * 64 + k2 * 32 + fk);
      bf16x8 bb = ld_frag(sWt + (ct * 16 + fr) * 64 + k2 * 32 + fk);
      acc = MFMA16(a, bb, acc);
    }
#pragma unroll
    for (int r = 0; r < 4; ++r)
      sT[(w * 16 + qr + r) * 64 + ct * 16 + fr] = f2bf(acc[r]);
  }
  __syncthreads();

  // K = T * E^T ; write K (bf16) into LDS (reuse sWt)
  unsigned short* sK = sWt;
#pragma unroll
  for (int ct = 0; ct < 4; ++ct) {
    f32x4 acc = {0.f, 0.f, 0.f, 0.f};
#pragma unroll
    for (int k2 = 0; k2 < 2; ++k2) {
      bf16x8 a = ld_frag(sT + (w * 16 + fr) * 64 + k2 * 32 + fk);
      bf16x8 bb = ld_frag(sE + (ct * 16 + fr) * 64 + k2 * 32 + fk);
      acc = MFMA16(a, bb, acc);
    }
#pragma unroll
    for (int r = 0; r < 4; ++r)
      sK[(w * 16 + qr + r) * 64 + ct * 16 + fr] = f2bf(acc[r]);
  }
  __syncthreads();

  // coalesced triangular emit (16B stores, pads zeroed)
  emit_tri(sK, triu + (size_t)b * KP, true, tid);
  emit_tri(sK, tril + (size_t)b * KP, false, tid);
}

// ---------------------------------------------------------------------------
// view = A[4096,2112] @ W[4096,2112]^T, 256^2 tile, BK=32, 1024 thr =
// 16 waves (4Mx4N), wave-tile 64x64. LDS 64 KiB dbuf -> 2 blocks/CU.
// Loop: {8 ds_read; stage t+1 (2 cp16); 16 MFMA; vmcnt(0); barrier} x 66.
// Swizzle for BK=32 (64B rows, bank wrap = 2 rows): chunk ^= (row>>1)&3.
// Bank position of lane (fr,fq) = (row&1, fq^((fr>>1)&3)) -> each aligned
// 16-lane group covers the 8 positions exactly 2x = free 2-way (m136).
// (R6's chunk^=(row&0x3) put fr=0,4,8,12 on one slot -> 4-way, 1.7e7 confl.)
// ---------------------------------------------------------------------------
__global__ __launch_bounds__(1024, 2) void gemm_views(
    const unsigned short* __restrict__ triu, const unsigned short* __restrict__ tril,
    const unsigned short* __restrict__ Wu, const unsigned short* __restrict__ Wl,
    float* __restrict__ dout)
{
  __shared__ __align__(16) unsigned short lds[32768];  // [2 buf][A|B][256*32]

  const int z = blockIdx.z;
  const unsigned short* Ag = z ? tril : triu;
  const unsigned short* Bg = z ? Wl : Wu;
  float* C = dout + (size_t)16777216 * (size_t)(1 + z);

  const int tid = threadIdx.x;
  const int lane = tid & 63, wv = tid >> 6;
  const int m0 = blockIdx.y << 8, n0 = blockIdx.x << 8;

  // ---- staging geometry: thread t covers row t/4 (0..255), 16 B chunk
  // (t%4)^((row>>1)&3) of the 32-k row (pre-swizzled global src, linear LDS).
  const int srow = tid >> 2;
  const int schk = (tid & 3) ^ ((srow >> 1) & 3);
  const unsigned short* gA = Ag + (size_t)(m0 + srow) * KP + schk * 8;
  const unsigned short* gB = Bg + (size_t)(n0 + srow) * KP + schk * 8;
  unsigned short* const dstA = lds + tid * 8;          // + buf*16384
  unsigned short* const dstB = lds + 8192 + tid * 8;   // + buf*16384

  // ---- fragment-read geometry (swizzled): frag k-chunk = fq ^ ((fr>>1)&3)
  // ((row>>1)&3 == (fr>>1)&3 since wave/mt row offsets are multiples of 16)
  const int fr = lane & 15, fq = lane >> 4;
  const int wm = (wv >> 2) << 6, wn = (wv & 3) << 6;   // wave tile origin
  const int kx = (fq ^ ((fr >> 1) & 3)) * 8;

  f32x4 acc[4][4] = {};
  bf16x8 a_[4], b_[4];

  // ---- prologue: stage tile 0 into buf 0
  cp16(gA, dstA);
  cp16(gB, dstB);
  VMWAIT(0);
  close_bar();

  for (int t = 0; t < NKT; ++t) {
    const int cb = t & 1, nb = cb ^ 1;
    const int tn = (t + 1 < NKT) ? t + 1 : NKT - 1;  // clamped dup is harmless
    // read current fragments (critical path to MFMA -> issue first)
    const unsigned short* ba = lds + cb * 16384;
#pragma unroll
    for (int mt = 0; mt < 4; ++mt)
      a_[mt] = ld_frag(ba + (wm + mt * 16 + fr) * 32 + kx);
#pragma unroll
    for (int nt = 0; nt < 4; ++nt)
      b_[nt] = ld_frag(ba + 8192 + (wn + nt * 16 + fr) * 32 + kx);
    // stage next tile
    cp16(gA + tn * 32, dstA + nb * 16384);
    cp16(gB + tn * 32, dstB + nb * 16384);
    // compute (compiler inserts lgkm waits on operand deps)
    __builtin_amdgcn_s_setprio(1);
#pragma unroll
    for (int mt = 0; mt < 4; ++mt)
#pragma unroll
      for (int nt = 0; nt < 4; ++nt)
        acc[mt][nt] = MFMA16(a_[mt], b_[nt], acc[mt][nt]);
    __builtin_amdgcn_s_setprio(0);
    VMWAIT(0);     // own cp16s landed; barrier makes all waves' visible
    close_bar();
  }

  // ---- epilogue: acc -> C
  const int qr = fq << 2;
  const int crow = m0 + wm + qr;
  const int ccol = n0 + wn + fr;
#pragma unroll
  for (int mt = 0; mt < 4; ++mt)
#pragma unroll
    for (int nt = 0; nt < 4; ++nt) {
      float* cp = C + (size_t)(crow + mt * 16) * 4096 + (ccol + nt * 16);
#pragma unroll
      for (int r = 0; r < 4; ++r) cp[(size_t)r * 4096] = acc[mt][nt][r];
    }
}

// ---------------------------------------------------------------------------
extern "C" void kernel_launch(void* const* d_in, const int* in_sizes, int n_in,
                              void* d_out, int out_size, void* d_ws, size_t ws_size,
                              hipStream_t stream) {
  const float* feat  = (const float*)d_in[0];   // [4096,64,64]
  const float* kpW   = (const float*)d_in[1];   // [64,64]
  const float* Wtriu = (const float*)d_in[2];   // [4096,2080]
  const float* Wtril = (const float*)d_in[3];   // [4096,2080]
  float* out = (float*)d_out;                   // [emb_flat | view1 | view2]

  // workspace layout (bf16, K-padded to 2112), ~69.2 MB
  const size_t per = (size_t)4096 * KP;
  unsigned short* triu_bf = (unsigned short*)d_ws;
  unsigned short* tril_bf = triu_bf + per;
  unsigned short* Wu_bf   = tril_bf + per;
  unsigned short* Wl_bf   = Wu_bf + per;

  prep_all<<<dim3(6144), dim3(256), 0, stream>>>(
      feat, kpW, Wtriu, Wtril, out, triu_bf, tril_bf, Wu_bf, Wl_bf);
  gemm_views<<<dim3(16, 16, 2), dim3(1024), 0, stream>>>(triu_bf, tril_bf, Wu_bf, Wl_bf, out);
}

// Round 8
// 421.075 us; speedup vs baseline: 1.0528x; 1.0528x over previous
//
#include <hip/hip_runtime.h>

typedef __bf16 bf16x8 __attribute__((ext_vector_type(8)));
typedef float f32x4 __attribute__((ext_vector_type(4)));
typedef unsigned short u16x4 __attribute__((ext_vector_type(4)));
typedef unsigned short u16x8 __attribute__((ext_vector_type(8)));

#define KP 2112   // padded K: 2080 + 32 = 33 * 64
#define NT 33     // K-tiles of 64

__device__ __forceinline__ unsigned short f2bf(float f) {
  unsigned int u = __builtin_bit_cast(unsigned int, f);
  u += 0x7FFFu + ((u >> 16) & 1u);   // round-to-nearest-even
  return (unsigned short)(u >> 16);
}

__device__ __forceinline__ bf16x8 ld_frag(const unsigned short* p) {
  return __builtin_bit_cast(bf16x8, *(const u16x8*)p);
}

#define MFMA16(a, b, c) __builtin_amdgcn_mfma_f32_16x16x32_bf16((a), (b), (c), 0, 0, 0)

// async global->LDS, 16B per lane (global_load_lds_dwordx4)
__device__ __forceinline__ void cp16(const void* g, void* l) {
  __builtin_amdgcn_global_load_lds(
      (const __attribute__((address_space(1))) unsigned int*)g,
      (__attribute__((address_space(3))) unsigned int*)l, 16, 0, 0);
}

// enter barrier with ds_reads in flight; drain after (overlap under skew).
// sched_barrier after the drain is load-bearing (rule #18).
__device__ __forceinline__ void gate() {
  __builtin_amdgcn_s_barrier();
  asm volatile("s_waitcnt lgkmcnt(0)" ::: "memory");
  __builtin_amdgcn_sched_barrier(0);
}
// closing barrier: no sched_barrier -> next-phase address VALU may migrate.
__device__ __forceinline__ void close_bar() {
  asm volatile("" ::: "memory");
  __builtin_amdgcn_s_barrier();
}

#define VMWAIT(N) asm volatile("s_waitcnt vmcnt(" #N ")" ::: "memory")

// ---------------------------------------------------------------------------
// Coalesced triangular emit: 2112 u16 per matrix as u16x8 per thread (+ tail
// jobs on tid<8). (i,j) recovered analytically from flat idx p via sqrt+fixup.
// ---------------------------------------------------------------------------
__device__ __forceinline__ void emit_tri(const unsigned short* __restrict__ sK,
                                         unsigned short* __restrict__ dst,
                                         bool upper, int tid) {
#pragma unroll
  for (int jj = 0; jj < 2; ++jj) {
    if (jj == 1 && tid >= 8) break;
    const int p0 = (jj == 0) ? tid * 8 : 2048 + tid * 8;
    int i, j;
    if (upper) {
      // U_i = i*(129-i)/2 rows start; row i spans [U_i, U_{i+1}) len 64-i
      float s = sqrtf(4160.25f - 2.0f * (float)p0);
      i = (int)(64.5f - s);
      if (i < 0) i = 0;
      if (i > 63) i = 63;
      while (i > 0 && i * (129 - i) / 2 > p0) --i;
      while (i < 63 && (i + 1) * (128 - i) / 2 <= p0) ++i;
      j = i + (p0 - i * (129 - i) / 2);
    } else {
      // T_i = i*(i+1)/2; row i spans [T_i, T_{i+1}) len i+1
      float s = sqrtf(8.0f * (float)p0 + 1.0f);
      i = (int)((s - 1.0f) * 0.5f);
      if (i < 0) i = 0;
      if (i > 63) i = 63;
      while (i > 0 && i * (i + 1) / 2 > p0) --i;
      while (i < 63 && (i + 1) * (i + 2) / 2 <= p0) ++i;
      j = p0 - i * (i + 1) / 2;
    }
    u16x8 o;
#pragma unroll
    for (int e = 0; e < 8; ++e) {
      const int p = p0 + e;
      o[e] = (p < 2080 && i < 64) ? sK[i * 64 + j] : (unsigned short)0;
      if (upper) { if (++j > 63) { ++i; j = i; } }
      else       { if (++j > i)  { ++i; j = 0; } }
    }
    *(u16x8*)(dst + p0) = o;
  }
}

// ---------------------------------------------------------------------------
// Fused prep: blocks [0,4096) = per-batch kp (E*W*E^T -> triu/tril + E copy);
// blocks [4096,6144) = W_triu/W_tril fp32->bf16 with K-pad (2 rows each).
// ---------------------------------------------------------------------------
__global__ __launch_bounds__(256) void prep_all(
    const float* __restrict__ E,        // [B,64,64]
    const float* __restrict__ Wkp,      // [64,64]
    const float* __restrict__ Wtriu,    // [4096,2080]
    const float* __restrict__ Wtril,    // [4096,2080]
    float* __restrict__ out0,           // [B,4096]
    unsigned short* __restrict__ triu,  // [B,2112] bf16
    unsigned short* __restrict__ tril,  // [B,2112] bf16
    unsigned short* __restrict__ Wu,    // [4096,2112] bf16
    unsigned short* __restrict__ Wl)    // [4096,2112] bf16
{
  const int bid = blockIdx.x;
  const int tid = threadIdx.x;

  if (bid >= 4096) {
    // ---- cvt path: 2 rows of each W matrix, coalesced float4 -> u16x4
    const int r0 = (bid - 4096) * 2;
#pragma unroll
    for (int q = 0; q < 4; ++q) {
      const int row = r0 + (q & 1);
      const float* src = (q < 2 ? Wtriu : Wtril) + (size_t)row * 2080;
      unsigned short* dst = (q < 2 ? Wu : Wl) + (size_t)row * KP;
      for (int c = tid; c < 528; c += 256) {   // u16x4 chunks per row
        u16x4 o = {0, 0, 0, 0};
        if (c < 520) {
          float4 v = *(const float4*)(src + c * 4);
          o[0] = f2bf(v.x); o[1] = f2bf(v.y); o[2] = f2bf(v.z); o[3] = f2bf(v.w);
        }
        ((u16x4*)dst)[c] = o;
      }
    }
    return;
  }

  // ---- batch path
  __shared__ __align__(16) unsigned short sE[64 * 64];
  __shared__ __align__(16) unsigned short sWt[64 * 64];  // reused as sK later
  __shared__ __align__(16) unsigned short sT[64 * 64];

  const int b = bid;
  const float* Eb = E + (size_t)b * 4096;
  float* o0 = out0 + (size_t)b * 4096;

#pragma unroll
  for (int it = 0; it < 4; ++it) {
    const int flat = it * 1024 + tid * 4;
    float4 v = *(const float4*)(Eb + flat);
    *(float4*)(o0 + flat) = v;                 // embs_flatten output (exact fp32)
    u16x4 e;
    e[0] = f2bf(v.x); e[1] = f2bf(v.y); e[2] = f2bf(v.z); e[3] = f2bf(v.w);
    *(u16x4*)(sE + flat) = e;
    float4 wv = *(const float4*)(Wkp + flat);  // inline W^T (row d, cols c0..+3)
    const int d = flat >> 6, c0 = flat & 63;
    sWt[(c0 + 0) * 64 + d] = f2bf(wv.x);
    sWt[(c0 + 1) * 64 + d] = f2bf(wv.y);
    sWt[(c0 + 2) * 64 + d] = f2bf(wv.z);
    sWt[(c0 + 3) * 64 + d] = f2bf(wv.w);
  }
  __syncthreads();

  const int lane = tid & 63, w = tid >> 6;
  const int fr = lane & 15;
  const int fk = (lane >> 4) << 3;
  const int qr = (lane >> 4) << 2;

  // T = Ebf * Wkp : wave w computes rows [w*16, w*16+16)
#pragma unroll
  for (int ct = 0; ct < 4; ++ct) {
    f32x4 acc = {0.f, 0.f, 0.f, 0.f};
#pragma unroll
    for (int k2 = 0; k2 < 2; ++k2) {
      bf16x8 a = ld_frag(sE + (w * 16 + fr) * 64 + k2 * 32 + fk);
      bf16x8 bb = ld_frag(sWt + (ct * 16 + fr) * 64 + k2 * 32 + fk);
      acc = MFMA16(a, bb, acc);
    }
#pragma unroll
    for (int r = 0; r < 4; ++r)
      sT[(w * 16 + qr + r) * 64 + ct * 16 + fr] = f2bf(acc[r]);
  }
  __syncthreads();

  // K = T * E^T ; write K (bf16) into LDS (reuse sWt)
  unsigned short* sK = sWt;
#pragma unroll
  for (int ct = 0; ct < 4; ++ct) {
    f32x4 acc = {0.f, 0.f, 0.f, 0.f};
#pragma unroll
    for (int k2 = 0; k2 < 2; ++k2) {
      bf16x8 a = ld_frag(sT + (w * 16 + fr) * 64 + k2 * 32 + fk);
      bf16x8 bb = ld_frag(sE + (ct * 16 + fr) * 64 + k2 * 32 + fk);
      acc = MFMA16(a, bb, acc);
    }
#pragma unroll
    for (int r = 0; r < 4; ++r)
      sK[(w * 16 + qr + r) * 64 + ct * 16 + fr] = f2bf(acc[r]);
  }
  __syncthreads();

  // coalesced triangular emit (16B stores, pads zeroed)
  emit_tri(sK, triu + (size_t)b * KP, true, tid);
  emit_tri(sK, tril + (size_t)b * KP, false, tid);
}

// ---------------------------------------------------------------------------
// view = A[4096,2112] @ W[4096,2112]^T, 256^2 tile, BK=64, 512 thr (2Mx4N
// waves, 128x64/wave) -- R5 structure (best measured), launched per-z so
// prep_all can surface in the top-5 (diagnostic). Phases: {reads; stage;
// barrier; lgkmcnt(0); setprio1; 16 MFMA; setprio0; [vmcnt]; barrier}.
// ---------------------------------------------------------------------------
__global__ __launch_bounds__(512, 2) void gemm_views(
    const unsigned short* __restrict__ triu, const unsigned short* __restrict__ tril,
    const unsigned short* __restrict__ Wu, const unsigned short* __restrict__ Wl,
    float* __restrict__ dout, int z)
{
  __shared__ __align__(16) unsigned short lds[65536];  // [2 buf][A|B][256*64]

  const unsigned short* Ag = z ? tril : triu;
  const unsigned short* Bg = z ? Wl : Wu;
  float* C = dout + (size_t)16777216 * (size_t)(1 + z);

  const int tid = threadIdx.x;
  const int lane = tid & 63, wv = tid >> 6;
  const int m0 = blockIdx.y << 8, n0 = blockIdx.x << 8;

  // ---- staging geometry: per cp16 a wave covers 8 rows x 64 k (1024 B linear)
  const int lr = lane >> 3;                    // row within wave's 8-row group
  const int cuch = (lane & 7) ^ lr;            // pre-swizzled global chunk
  const int rA = wv * 8 + lr;                                  // + OFF
  const int rB = (wv & 3) * 8 + (wv >> 2) * 64 + lr;           // + OFF
  const unsigned short* gA = Ag + (size_t)(m0 + rA) * KP + cuch * 8;
  const unsigned short* gB = Bg + (size_t)(n0 + rB) * KP + cuch * 8;
  const int dA = tid * 8;                                      // u16 idx
  const int dB = (wv & 3) * 512 + (wv >> 2) * 4096 + lane * 8;

  // ---- fragment-read geometry (swizzled)
  const int fr = lane & 15, fq = lane >> 4;
  const int rowA0 = (wv >> 2) * 128 + fr;
  const int rowB0 = (wv & 3) * 64 + fr;

  f32x4 acc[8][4] = {};
  bf16x8 a_[4], aX_[4], b0_[4], b1_[4];

#define STAGE_A(B_, KT, OFF) do { \
    cp16(gA + (size_t)(OFF) * KP + (KT) * 64, lds + (B_) * 32768 + (OFF) * 64 + dA); \
    cp16(gA + (size_t)((OFF) + 128) * KP + (KT) * 64, \
         lds + (B_) * 32768 + ((OFF) + 128) * 64 + dA); \
  } while (0)
#define STAGE_B(B_, KT, OFF) do { \
    cp16(gB + (size_t)(OFF) * KP + (KT) * 64, \
         lds + (B_) * 32768 + 16384 + (OFF) * 64 + dB); \
    cp16(gB + (size_t)((OFF) + 128) * KP + (KT) * 64, \
         lds + (B_) * 32768 + 16384 + ((OFF) + 128) * 64 + dB); \
  } while (0)
// read 4 A-frags (one MH-half, one k-half) / 4 B-frags (all nt, one k-half)
#define LDA(S, B_, MH, KH) do { _Pragma("unroll") \
    for (int mt = 0; mt < 4; ++mt) \
      S[mt] = ld_frag(lds + (B_) * 32768 + (rowA0 + (MH) * 64 + mt * 16) * 64 + \
                      ((((KH) * 4 + fq) ^ (fr & 7)) * 8)); \
  } while (0)
#define LDB(S, B_, KH) do { _Pragma("unroll") \
    for (int nt = 0; nt < 4; ++nt) \
      S[nt] = ld_frag(lds + (B_) * 32768 + 16384 + (rowB0 + nt * 16) * 64 + \
                      ((((KH) * 4 + fq) ^ (fr & 7)) * 8)); \
  } while (0)
#define PH_MFMA(AS, BS, MH) do { \
    __builtin_amdgcn_s_setprio(1); \
    _Pragma("unroll") for (int mt = 0; mt < 4; ++mt) \
    _Pragma("unroll") for (int nt = 0; nt < 4; ++nt) \
      acc[(MH) * 4 + mt][nt] = MFMA16(AS[mt], BS[nt], acc[(MH) * 4 + mt][nt]); \
    __builtin_amdgcn_s_setprio(0); \
  } while (0)

  // ---- prologue: tile 0 fully + tile 1 {B0,B32,A0}
  STAGE_A(0, 0, 0);
  STAGE_B(0, 0, 0);
  STAGE_B(0, 0, 32);
  STAGE_A(0, 0, 64);
  STAGE_B(1, 1, 0);
  STAGE_B(1, 1, 32);
  STAGE_A(1, 1, 0);
  VMWAIT(6);           // tile-0 (8 bundles) landed; tile-1 (6) in flight
  close_bar();

  for (int t = 0; t < NT; ++t) {
    const int cb = t & 1, nb = cb ^ 1;
    const int t1 = (t + 1 < NT) ? t + 1 : NT - 1;   // clamp keeps vmcnt uniform
    const int t2 = (t + 2 < NT) ? t + 2 : NT - 1;   // (clamped stages are
                                                    //  never-read but safe)
    // p0: reads a[MH0,k0], b[k0]; stage nb A-MH1; compute (MH0,k0)
    LDA(a_, cb, 0, 0);
    LDB(b0_, cb, 0);
    STAGE_A(nb, t1, 64);
    gate();
    PH_MFMA(a_, b0_, 0);
    close_bar();
    // p1: reads a[MH1,k0], b[k1] (early); compute (MH1,k0)
    LDA(a_, cb, 1, 0);
    LDB(b1_, cb, 1);
    gate();
    PH_MFMA(a_, b0_, 1);
    close_bar();
    // p2: reads a[MH1,k1] + a[MH0,k1] (early); stage cb B0(t+2); compute (MH1,k1)
    LDA(a_, cb, 1, 1);
    LDA(aX_, cb, 0, 1);
    STAGE_B(cb, t2, 0);
    gate();
    PH_MFMA(a_, b1_, 1);
    VMWAIT(4);   // drains t+1 stages issued at p2/p3 of t-1 (B0,B32,A0 of nb)
    close_bar();
    // p3: no reads; stage cb B32(t+2) + A0(t+2); compute (MH0,k1)
    STAGE_B(cb, t2, 32);
    STAGE_A(cb, t2, 0);
    gate();
    PH_MFMA(aX_, b1_, 0);
    VMWAIT(6);   // drains this tile's p0 stage (nb A-MH1) before t+1 p1 reads
    close_bar();
  }

  // ---- epilogue: acc -> C
  const int qr = fq << 2;
  const int crow = m0 + (wv >> 2) * 128 + qr;
  const int ccol = n0 + (wv & 3) * 64 + fr;
#pragma unroll
  for (int mt = 0; mt < 8; ++mt)
#pragma unroll
    for (int nt = 0; nt < 4; ++nt) {
      float* cp = C + (size_t)(crow + mt * 16) * 4096 + (ccol + nt * 16);
#pragma unroll
      for (int r = 0; r < 4; ++r) cp[(size_t)r * 4096] = acc[mt][nt][r];
    }
#undef STAGE_A
#undef STAGE_B
#undef LDA
#undef LDB
#undef PH_MFMA
}

// ---------------------------------------------------------------------------
extern "C" void kernel_launch(void* const* d_in, const int* in_sizes, int n_in,
                              void* d_out, int out_size, void* d_ws, size_t ws_size,
                              hipStream_t stream) {
  const float* feat  = (const float*)d_in[0];   // [4096,64,64]
  const float* kpW   = (const float*)d_in[1];   // [64,64]
  const float* Wtriu = (const float*)d_in[2];   // [4096,2080]
  const float* Wtril = (const float*)d_in[3];   // [4096,2080]
  float* out = (float*)d_out;                   // [emb_flat | view1 | view2]

  // workspace layout (bf16, K-padded to 2112), ~69.2 MB
  const size_t per = (size_t)4096 * KP;
  unsigned short* triu_bf = (unsigned short*)d_ws;
  unsigned short* tril_bf = triu_bf + per;
  unsigned short* Wu_bf   = tril_bf + per;
  unsigned short* Wl_bf   = Wu_bf + per;

  prep_all<<<dim3(6144), dim3(256), 0, stream>>>(
      feat, kpW, Wtriu, Wtril, out, triu_bf, tril_bf, Wu_bf, Wl_bf);
  gemm_views<<<dim3(16, 16), dim3(512), 0, stream>>>(triu_bf, tril_bf, Wu_bf, Wl_bf, out, 0);
  gemm_views<<<dim3(16, 16), dim3(512), 0, stream>>>(triu_bf, tril_bf, Wu_bf, Wl_bf, out, 1);
}

// Round 9
// 413.359 us; speedup vs baseline: 1.0725x; 1.0187x over previous
//
#include <hip/hip_runtime.h>

typedef __bf16 bf16x8 __attribute__((ext_vector_type(8)));
typedef float f32x4 __attribute__((ext_vector_type(4)));
typedef unsigned short u16x4 __attribute__((ext_vector_type(4)));
typedef unsigned short u16x8 __attribute__((ext_vector_type(8)));

#define KP 2112   // padded K: 2080 + 32 = 33 * 64
#define NT 33     // K-tiles of 64

__device__ __forceinline__ unsigned short f2bf(float f) {
  unsigned int u = __builtin_bit_cast(unsigned int, f);
  u += 0x7FFFu + ((u >> 16) & 1u);   // round-to-nearest-even
  return (unsigned short)(u >> 16);
}

__device__ __forceinline__ bf16x8 ld_frag(const unsigned short* p) {
  return __builtin_bit_cast(bf16x8, *(const u16x8*)p);
}

#define MFMA16(a, b, c) __builtin_amdgcn_mfma_f32_16x16x32_bf16((a), (b), (c), 0, 0, 0)

// async global->LDS, 16B per lane (global_load_lds_dwordx4)
__device__ __forceinline__ void cp16(const void* g, void* l) {
  __builtin_amdgcn_global_load_lds(
      (const __attribute__((address_space(1))) unsigned int*)g,
      (__attribute__((address_space(3))) unsigned int*)l, 16, 0, 0);
}

// enter barrier with ds_reads in flight; drain after (reads were issued one
// phase earlier -> drain is cheap). sched_barrier is load-bearing (rule #18).
__device__ __forceinline__ void gate() {
  __builtin_amdgcn_s_barrier();
  asm volatile("s_waitcnt lgkmcnt(0)" ::: "memory");
  __builtin_amdgcn_sched_barrier(0);
}
__device__ __forceinline__ void close_bar() {
  asm volatile("" ::: "memory");
  __builtin_amdgcn_s_barrier();
}

#define VMWAIT(N) asm volatile("s_waitcnt vmcnt(" #N ")" ::: "memory")

// ---------------------------------------------------------------------------
// Coalesced triangular emit: 2112 u16 per matrix as u16x8 per thread (+ tail
// jobs on tid<8). (i,j) recovered analytically from flat idx p via sqrt+fixup.
// ---------------------------------------------------------------------------
__device__ __forceinline__ void emit_tri(const unsigned short* __restrict__ sK,
                                         unsigned short* __restrict__ dst,
                                         bool upper, int tid) {
#pragma unroll
  for (int jj = 0; jj < 2; ++jj) {
    if (jj == 1 && tid >= 8) break;
    const int p0 = (jj == 0) ? tid * 8 : 2048 + tid * 8;
    int i, j;
    if (upper) {
      // U_i = i*(129-i)/2 rows start; row i spans [U_i, U_{i+1}) len 64-i
      float s = sqrtf(4160.25f - 2.0f * (float)p0);
      i = (int)(64.5f - s);
      if (i < 0) i = 0;
      if (i > 63) i = 63;
      while (i > 0 && i * (129 - i) / 2 > p0) --i;
      while (i < 63 && (i + 1) * (128 - i) / 2 <= p0) ++i;
      j = i + (p0 - i * (129 - i) / 2);
    } else {
      // T_i = i*(i+1)/2; row i spans [T_i, T_{i+1}) len i+1
      float s = sqrtf(8.0f * (float)p0 + 1.0f);
      i = (int)((s - 1.0f) * 0.5f);
      if (i < 0) i = 0;
      if (i > 63) i = 63;
      while (i > 0 && i * (i + 1) / 2 > p0) --i;
      while (i < 63 && (i + 1) * (i + 2) / 2 <= p0) ++i;
      j = p0 - i * (i + 1) / 2;
    }
    u16x8 o;
#pragma unroll
    for (int e = 0; e < 8; ++e) {
      const int p = p0 + e;
      o[e] = (p < 2080 && i < 64) ? sK[i * 64 + j] : (unsigned short)0;
      if (upper) { if (++j > 63) { ++i; j = i; } }
      else       { if (++j > i)  { ++i; j = 0; } }
    }
    *(u16x8*)(dst + p0) = o;
  }
}

// ---------------------------------------------------------------------------
// Fused prep: blocks [0,4096) = per-batch kp (E*W*E^T -> triu/tril + E copy);
// blocks [4096,6144) = W_triu/W_tril fp32->bf16 with K-pad (2 rows each).
// Measured ~35 us vs ~41 us traffic roofline -> done.
// ---------------------------------------------------------------------------
__global__ __launch_bounds__(256) void prep_all(
    const float* __restrict__ E,        // [B,64,64]
    const float* __restrict__ Wkp,      // [64,64]
    const float* __restrict__ Wtriu,    // [4096,2080]
    const float* __restrict__ Wtril,    // [4096,2080]
    float* __restrict__ out0,           // [B,4096]
    unsigned short* __restrict__ triu,  // [B,2112] bf16
    unsigned short* __restrict__ tril,  // [B,2112] bf16
    unsigned short* __restrict__ Wu,    // [4096,2112] bf16
    unsigned short* __restrict__ Wl)    // [4096,2112] bf16
{
  const int bid = blockIdx.x;
  const int tid = threadIdx.x;

  if (bid >= 4096) {
    // ---- cvt path: 2 rows of each W matrix, coalesced float4 -> u16x4
    const int r0 = (bid - 4096) * 2;
#pragma unroll
    for (int q = 0; q < 4; ++q) {
      const int row = r0 + (q & 1);
      const float* src = (q < 2 ? Wtriu : Wtril) + (size_t)row * 2080;
      unsigned short* dst = (q < 2 ? Wu : Wl) + (size_t)row * KP;
      for (int c = tid; c < 528; c += 256) {   // u16x4 chunks per row
        u16x4 o = {0, 0, 0, 0};
        if (c < 520) {
          float4 v = *(const float4*)(src + c * 4);
          o[0] = f2bf(v.x); o[1] = f2bf(v.y); o[2] = f2bf(v.z); o[3] = f2bf(v.w);
        }
        ((u16x4*)dst)[c] = o;
      }
    }
    return;
  }

  // ---- batch path
  __shared__ __align__(16) unsigned short sE[64 * 64];
  __shared__ __align__(16) unsigned short sWt[64 * 64];  // reused as sK later
  __shared__ __align__(16) unsigned short sT[64 * 64];

  const int b = bid;
  const float* Eb = E + (size_t)b * 4096;
  float* o0 = out0 + (size_t)b * 4096;

#pragma unroll
  for (int it = 0; it < 4; ++it) {
    const int flat = it * 1024 + tid * 4;
    float4 v = *(const float4*)(Eb + flat);
    *(float4*)(o0 + flat) = v;                 // embs_flatten output (exact fp32)
    u16x4 e;
    e[0] = f2bf(v.x); e[1] = f2bf(v.y); e[2] = f2bf(v.z); e[3] = f2bf(v.w);
    *(u16x4*)(sE + flat) = e;
    float4 wv = *(const float4*)(Wkp + flat);  // inline W^T (row d, cols c0..+3)
    const int d = flat >> 6, c0 = flat & 63;
    sWt[(c0 + 0) * 64 + d] = f2bf(wv.x);
    sWt[(c0 + 1) * 64 + d] = f2bf(wv.y);
    sWt[(c0 + 2) * 64 + d] = f2bf(wv.z);
    sWt[(c0 + 3) * 64 + d] = f2bf(wv.w);
  }
  __syncthreads();

  const int lane = tid & 63, w = tid >> 6;
  const int fr = lane & 15;
  const int fk = (lane >> 4) << 3;
  const int qr = (lane >> 4) << 2;

  // T = Ebf * Wkp : wave w computes rows [w*16, w*16+16)
#pragma unroll
  for (int ct = 0; ct < 4; ++ct) {
    f32x4 acc = {0.f, 0.f, 0.f, 0.f};
#pragma unroll
    for (int k2 = 0; k2 < 2; ++k2) {
      bf16x8 a = ld_frag(sE + (w * 16 + fr) * 64 + k2 * 32 + fk);
      bf16x8 bb = ld_frag(sWt + (ct * 16 + fr) * 64 + k2 * 32 + fk);
      acc = MFMA16(a, bb, acc);
    }
#pragma unroll
    for (int r = 0; r < 4; ++r)
      sT[(w * 16 + qr + r) * 64 + ct * 16 + fr] = f2bf(acc[r]);
  }
  __syncthreads();

  // K = T * E^T ; write K (bf16) into LDS (reuse sWt)
  unsigned short* sK = sWt;
#pragma unroll
  for (int ct = 0; ct < 4; ++ct) {
    f32x4 acc = {0.f, 0.f, 0.f, 0.f};
#pragma unroll
    for (int k2 = 0; k2 < 2; ++k2) {
      bf16x8 a = ld_frag(sT + (w * 16 + fr) * 64 + k2 * 32 + fk);
      bf16x8 bb = ld_frag(sE + (ct * 16 + fr) * 64 + k2 * 32 + fk);
      acc = MFMA16(a, bb, acc);
    }
#pragma unroll
    for (int r = 0; r < 4; ++r)
      sK[(w * 16 + qr + r) * 64 + ct * 16 + fr] = f2bf(acc[r]);
  }
  __syncthreads();

  // coalesced triangular emit (16B stores, pads zeroed)
  emit_tri(sK, triu + (size_t)b * KP, true, tid);
  emit_tri(sK, tril + (size_t)b * KP, false, tid);
}

// ---------------------------------------------------------------------------
// view = A[4096,2112] @ W[4096,2112]^T, 256^2 tile, BK=64, 512 thr (2Mx4N
// waves, 128x64/wave). m201-faithful schedule: per phase {gate; 16 MFMA on
// regs read LAST phase; post: reads for next phase (ping-pong aE_/aO_,
// b0_/b1_) + stages; close_bar}. ONE counted VMWAIT(6) per K-tile at p3
// (drains exactly tile t+1's 8 bundles, leaves t+2's 6 in flight).
// LDS XOR-swizzle (row&7) on pre-swizzled global src + swizzled ds_read.
// ---------------------------------------------------------------------------
__global__ __launch_bounds__(512, 2) void gemm_views(
    const unsigned short* __restrict__ triu, const unsigned short* __restrict__ tril,
    const unsigned short* __restrict__ Wu, const unsigned short* __restrict__ Wl,
    float* __restrict__ dout)
{
  __shared__ __align__(16) unsigned short lds[65536];  // [2 buf][A|B][256*64]

  const int z = blockIdx.z;
  const unsigned short* Ag = z ? tril : triu;
  const unsigned short* Bg = z ? Wl : Wu;
  float* C = dout + (size_t)16777216 * (size_t)(1 + z);

  const int tid = threadIdx.x;
  const int lane = tid & 63, wv = tid >> 6;
  const int m0 = blockIdx.y << 8, n0 = blockIdx.x << 8;

  // ---- staging geometry: per cp16 a wave covers 8 rows x 64 k (1024 B linear)
  const int lr = lane >> 3;                    // row within wave's 8-row group
  const int cuch = (lane & 7) ^ lr;            // pre-swizzled global chunk
  const int rA = wv * 8 + lr;                                  // + OFF
  const int rB = (wv & 3) * 8 + (wv >> 2) * 64 + lr;           // + OFF
  const unsigned short* gA = Ag + (size_t)(m0 + rA) * KP + cuch * 8;
  const unsigned short* gB = Bg + (size_t)(n0 + rB) * KP + cuch * 8;
  const int dA = tid * 8;                                      // u16 idx
  const int dB = (wv & 3) * 512 + (wv >> 2) * 4096 + lane * 8;

  // ---- fragment-read geometry (swizzled)
  const int fr = lane & 15, fq = lane >> 4;
  const int rowA0 = (wv >> 2) * 128 + fr;
  const int rowB0 = (wv & 3) * 64 + fr;

  f32x4 acc[8][4] = {};
  bf16x8 aE_[4], aO_[4], b0_[4], b1_[4];   // ping-pong fragment sets

#define STAGE_A(B_, KT, OFF) do { \
    cp16(gA + (size_t)(OFF) * KP + (KT) * 64, lds + (B_) * 32768 + (OFF) * 64 + dA); \
    cp16(gA + (size_t)((OFF) + 128) * KP + (KT) * 64, \
         lds + (B_) * 32768 + ((OFF) + 128) * 64 + dA); \
  } while (0)
#define STAGE_B(B_, KT, OFF) do { \
    cp16(gB + (size_t)(OFF) * KP + (KT) * 64, \
         lds + (B_) * 32768 + 16384 + (OFF) * 64 + dB); \
    cp16(gB + (size_t)((OFF) + 128) * KP + (KT) * 64, \
         lds + (B_) * 32768 + 16384 + ((OFF) + 128) * 64 + dB); \
  } while (0)
// read 4 A-frags (one MH-half, one k-half) / 4 B-frags (all nt, one k-half)
#define LDA(S, B_, MH, KH) do { _Pragma("unroll") \
    for (int mt = 0; mt < 4; ++mt) \
      S[mt] = ld_frag(lds + (B_) * 32768 + (rowA0 + (MH) * 64 + mt * 16) * 64 + \
                      ((((KH) * 4 + fq) ^ (fr & 7)) * 8)); \
  } while (0)
#define LDB(S, B_, KH) do { _Pragma("unroll") \
    for (int nt = 0; nt < 4; ++nt) \
      S[nt] = ld_frag(lds + (B_) * 32768 + 16384 + (rowB0 + nt * 16) * 64 + \
                      ((((KH) * 4 + fq) ^ (fr & 7)) * 8)); \
  } while (0)
#define PH_MFMA(AS, BS, MH) do { \
    __builtin_amdgcn_s_setprio(1); \
    _Pragma("unroll") for (int mt = 0; mt < 4; ++mt) \
    _Pragma("unroll") for (int nt = 0; nt < 4; ++nt) \
      acc[(MH) * 4 + mt][nt] = MFMA16(AS[mt], BS[nt], acc[(MH) * 4 + mt][nt]); \
    __builtin_amdgcn_s_setprio(0); \
  } while (0)

  // ---- prologue: tile 0 fully + tile 1 {B0,B32,A0}; initial reads
  STAGE_A(0, 0, 0);
  STAGE_A(0, 0, 64);
  STAGE_B(0, 0, 0);
  STAGE_B(0, 0, 32);
  STAGE_B(1, 1, 0);
  STAGE_B(1, 1, 32);
  STAGE_A(1, 1, 0);
  VMWAIT(6);           // tile-0 (8 bundles) landed; tile-1 (6) in flight
  close_bar();
  LDA(aE_, 0, 0, 0);   // a[MH0,k0](0)
  LDB(b0_, 0, 0);      // b[k0](0)

  for (int t = 0; t < NT; ++t) {
    const int cb = t & 1, nb = cb ^ 1;
    const int t1 = (t + 1 < NT) ? t + 1 : NT - 1;   // clamp keeps vmcnt uniform
    const int t2 = (t + 2 < NT) ? t + 2 : NT - 1;   // (clamped stages unread)
    // p0: MFMA (MH0,k0)[aE_,b0_]; post: read a[MH1,k0]; stage SA64(nb,t+1)
    gate();
    PH_MFMA(aE_, b0_, 0);
    LDA(aO_, cb, 1, 0);
    STAGE_A(nb, t1, 64);
    close_bar();
    // p1: MFMA (MH1,k0)[aO_,b0_]; post: read a[MH1,k1] + b[k1]
    gate();
    PH_MFMA(aO_, b0_, 1);
    LDA(aE_, cb, 1, 1);
    LDB(b1_, cb, 1);
    close_bar();
    // p2: MFMA (MH1,k1)[aE_,b1_]; post: read a[MH0,k1]; stage SB0(cb,t+2)
    gate();
    PH_MFMA(aE_, b1_, 1);
    LDA(aO_, cb, 0, 1);
    STAGE_B(cb, t2, 0);
    close_bar();
    // p3: MFMA (MH0,k1)[aO_,b1_]; post: stage SB32+SA0(cb,t+2);
    //     VMWAIT(6) drains ALL of tile t+1's bundles; then next-tile reads
    gate();
    PH_MFMA(aO_, b1_, 0);
    STAGE_B(cb, t2, 32);
    STAGE_A(cb, t2, 0);
    VMWAIT(6);
    LDA(aE_, nb, 0, 0);
    LDB(b0_, nb, 0);
    close_bar();
  }

  // ---- epilogue: acc -> C
  const int qr = fq << 2;
  const int crow = m0 + (wv >> 2) * 128 + qr;
  const int ccol = n0 + (wv & 3) * 64 + fr;
#pragma unroll
  for (int mt = 0; mt < 8; ++mt)
#pragma unroll
    for (int nt = 0; nt < 4; ++nt) {
      float* cp = C + (size_t)(crow + mt * 16) * 4096 + (ccol + nt * 16);
#pragma unroll
      for (int r = 0; r < 4; ++r) cp[(size_t)r * 4096] = acc[mt][nt][r];
    }
#undef STAGE_A
#undef STAGE_B
#undef LDA
#undef LDB
#undef PH_MFMA
}

// ---------------------------------------------------------------------------
extern "C" void kernel_launch(void* const* d_in, const int* in_sizes, int n_in,
                              void* d_out, int out_size, void* d_ws, size_t ws_size,
                              hipStream_t stream) {
  const float* feat  = (const float*)d_in[0];   // [4096,64,64]
  const float* kpW   = (const float*)d_in[1];   // [64,64]
  const float* Wtriu = (const float*)d_in[2];   // [4096,2080]
  const float* Wtril = (const float*)d_in[3];   // [4096,2080]
  float* out = (float*)d_out;                   // [emb_flat | view1 | view2]

  // workspace layout (bf16, K-padded to 2112), ~69.2 MB
  const size_t per = (size_t)4096 * KP;
  unsigned short* triu_bf = (unsigned short*)d_ws;
  unsigned short* tril_bf = triu_bf + per;
  unsigned short* Wu_bf   = tril_bf + per;
  unsigned short* Wl_bf   = Wu_bf + per;

  prep_all<<<dim3(6144), dim3(256), 0, stream>>>(
      feat, kpW, Wtriu, Wtril, out, triu_bf, tril_bf, Wu_bf, Wl_bf);
  gemm_views<<<dim3(16, 16, 2), dim3(512), 0, stream>>>(triu_bf, tril_bf, Wu_bf, Wl_bf, out);
}